// Round 1
// baseline (4711.976 us; speedup 1.0000x reference)
//
#include <hip/hip_runtime.h>
#include <stdint.h>

// Problem constants
// V=32000, E=256, H=512, S=128, B=32, T=32

using short8 = __attribute__((ext_vector_type(8))) short;
using f32x4  = __attribute__((ext_vector_type(4))) float;

__device__ __forceinline__ short f2bf(float x){
  unsigned u = __float_as_uint(x);
  unsigned r = (u + 0x7fffu + ((u >> 16) & 1u)) >> 16;
  return (short)(unsigned short)r;
}
__device__ __forceinline__ float sigmf(float x){ return 1.0f/(1.0f + __expf(-x)); }

// ---------------------------------------------------------------------------
// zero kernel (grid-stride)
__global__ void k_zero(float* __restrict__ p, int n){
  int i = blockIdx.x*256 + threadIdx.x;
  const int stride = gridDim.x*256;
  for (; i < n; i += stride) p[i] = 0.f;
}

// ---------------------------------------------------------------------------
// embedding gather -> bf16 rows. blocks 0..4095: src rows; 4096..5119: trg rows (pad>=992 zeroed)
__global__ __launch_bounds__(256) void k_gather(
    const int* __restrict__ src, const int* __restrict__ trg,
    const float* __restrict__ embed,
    short* __restrict__ emb_src_bf, short* __restrict__ emb_trg_bf)
{
  const int row = blockIdx.x, tid = threadIdx.x;
  if (row < 4096){
    const int tok = src[row];
    emb_src_bf[(size_t)row*256 + tid] = f2bf(embed[(size_t)tok*256 + tid]);
  } else {
    const int r = row - 4096;      // 0..1023
    short v = 0;
    if (r < 992){ const int tok = trg[r]; v = f2bf(embed[(size_t)tok*256 + tid]); }
    emb_trg_bf[(size_t)r*256 + tid] = v;
  }
}

// ---------------------------------------------------------------------------
// MFMA GEMM: C[M,N] f32 = A_bf16[M,*lda*] @ W_f32[N,*ldw*]^T + bias0 + bias1
// 128x128 tile, 4 waves (2x2 of 64x64), BK=32, mfma_f32_16x16x32_bf16.
// W is converted f32->bf16 during staging. Store guard row<Mvalid; A must be
// padded to a multiple of 128 rows; N must be a multiple of 128.
__global__ __launch_bounds__(256) void k_gemm_aw(
    const short* __restrict__ A, int lda,
    const float* __restrict__ W, int ldw,
    float* __restrict__ C, int ldc,
    const float* __restrict__ bias0, const float* __restrict__ bias1,
    int Mvalid, int K)
{
  __shared__ __align__(16) short As[128*32];
  __shared__ __align__(16) short Bs[128*32];
  const int tid = threadIdx.x;
  const int bm = blockIdx.x, bn = blockIdx.y;
  const int w  = tid >> 6,  l  = tid & 63;
  const int wm = w >> 1,    wn = w & 1;
  const int lr = l & 15,    lk = l >> 4;

  const int r0 = tid >> 2;             // chunk rows
  const int s0 = (tid & 3) << 3;       // k-seg (elements)
  const int r1 = r0 + 64;

  const short* a0 = A + (size_t)(bm*128 + r0)*lda + s0;
  const short* a1 = A + (size_t)(bm*128 + r1)*lda + s0;
  const float* w0 = W + (size_t)(bn*128 + r0)*ldw + s0;
  const float* w1 = W + (size_t)(bn*128 + r1)*ldw + s0;

  const f32x4 zero4 = {0.f,0.f,0.f,0.f};
  f32x4 acc[4][4];
  #pragma unroll
  for (int mi=0;mi<4;mi++){
    #pragma unroll
    for (int ni=0;ni<4;ni++) acc[mi][ni] = zero4;
  }

  for (int k0 = 0; k0 < K; k0 += 32){
    short8 va0 = *(const short8*)(a0 + k0);
    short8 va1 = *(const short8*)(a1 + k0);
    float4 f00 = *(const float4*)(w0 + k0);
    float4 f01 = *(const float4*)(w0 + k0 + 4);
    float4 f10 = *(const float4*)(w1 + k0);
    float4 f11 = *(const float4*)(w1 + k0 + 4);
    short8 vb0, vb1;
    vb0[0]=f2bf(f00.x); vb0[1]=f2bf(f00.y); vb0[2]=f2bf(f00.z); vb0[3]=f2bf(f00.w);
    vb0[4]=f2bf(f01.x); vb0[5]=f2bf(f01.y); vb0[6]=f2bf(f01.z); vb0[7]=f2bf(f01.w);
    vb1[0]=f2bf(f10.x); vb1[1]=f2bf(f10.y); vb1[2]=f2bf(f10.z); vb1[3]=f2bf(f10.w);
    vb1[4]=f2bf(f11.x); vb1[5]=f2bf(f11.y); vb1[6]=f2bf(f11.z); vb1[7]=f2bf(f11.w);

    __syncthreads();                       // prev iteration's ds_reads done
    *((short8*)As + tid)       = va0;
    *((short8*)As + tid + 256) = va1;
    *((short8*)Bs + tid)       = vb0;
    *((short8*)Bs + tid + 256) = vb1;
    __syncthreads();                       // staging visible

    short8 af[4], bfr[4];
    #pragma unroll
    for (int mi=0;mi<4;mi++) af[mi]  = *(const short8*)&As[(wm*64 + mi*16 + lr)*32 + (lk<<3)];
    #pragma unroll
    for (int ni=0;ni<4;ni++) bfr[ni] = *(const short8*)&Bs[(wn*64 + ni*16 + lr)*32 + (lk<<3)];
    #pragma unroll
    for (int mi=0;mi<4;mi++){
      #pragma unroll
      for (int ni=0;ni<4;ni++)
        acc[mi][ni] = __builtin_amdgcn_mfma_f32_16x16x32_bf16(af[mi], bfr[ni], acc[mi][ni], 0,0,0);
    }
  }

  #pragma unroll
  for (int mi=0;mi<4;mi++){
    const int rb = bm*128 + wm*64 + mi*16 + (lk<<2);
    #pragma unroll
    for (int ni=0;ni<4;ni++){
      const int col = bn*128 + wn*64 + ni*16 + lr;
      float bv = 0.f;
      if (bias0) bv += bias0[col];
      if (bias1) bv += bias1[col];
      #pragma unroll
      for (int r=0;r<4;r++){
        const int row = rb + r;
        if (row < Mvalid) C[(size_t)row*ldc + col] = acc[mi][ni][r] + bv;
      }
    }
  }
}

// ---------------------------------------------------------------------------
// LSTM step core: z[b][j] = pre[b][j] (+bias0[j]+bias1[j]) + xa[b]·Wa[j] (+ xb[b]·Wb[j])
// then gates (i,f,g,o) -> c,h. Grid: 256 blocks (k-chunks of 2), 256 threads.
// thread = b + 32*gate + 128*kl.
__device__ __forceinline__ void step_core(
    const float* __restrict__ pre,
    const float* __restrict__ bias0, const float* __restrict__ bias1,
    const float* __restrict__ xa, const float* __restrict__ Wa, int ldwa,
    const float* __restrict__ xb, const float* __restrict__ Wb, int ldwb,
    float* __restrict__ c_st,
    float* __restrict__ h_f32,
    float* __restrict__ h_seq,
    short* __restrict__ h_bf16,
    float* x_lds, float* zbuf, int kchunk)
{
  const int tid  = threadIdx.x;
  const int b    = tid & 31;
  const int k    = (kchunk << 1) + (tid >> 7);
  const int j    = (((tid >> 5) & 3) << 9) + k;
  float acc = 0.0f;
  if (pre)   acc  = pre[b*2048 + j];
  if (bias0) acc += bias0[j];
  if (bias1) acc += bias1[j];
  const int nseg = xb ? 4 : 2;
  for (int seg = 0; seg < nseg; ++seg){
    const float* x = (seg < 2) ? xa : xb;
    const int ko = (seg & 1) << 8;
    __syncthreads();
    #pragma unroll
    for (int i = 0; i < 8; ++i){
      const int idx = tid + (i << 8);                 // 0..2047 float4 slots
      const int bb = idx >> 6, kk = (idx & 63) << 2;
      *(float4*)&x_lds[bb*260 + kk] = *(const float4*)&x[bb*512 + ko + kk];
    }
    __syncthreads();
    const float* wr = ((seg < 2) ? (Wa + (size_t)j*ldwa) : (Wb + (size_t)j*ldwb)) + ko;
    const float* hx = &x_lds[b*260];
    float4 s4 = {0.f,0.f,0.f,0.f};
    #pragma unroll 4
    for (int kk = 0; kk < 256; kk += 4){
      const float4 wv = *(const float4*)&wr[kk];
      const float4 hv = *(const float4*)&hx[kk];
      s4.x = fmaf(wv.x, hv.x, s4.x);
      s4.y = fmaf(wv.y, hv.y, s4.y);
      s4.z = fmaf(wv.z, hv.z, s4.z);
      s4.w = fmaf(wv.w, hv.w, s4.w);
    }
    acc += (s4.x + s4.y) + (s4.z + s4.w);
  }
  zbuf[tid] = acc;
  __syncthreads();
  if (tid < 64){
    const int kl2 = tid >> 5, b2 = tid & 31;
    const int k2  = (kchunk << 1) + kl2;
    const int zb  = (kl2 << 7) + b2;
    const float zi = zbuf[zb], zf = zbuf[zb+32], zg = zbuf[zb+64], zo = zbuf[zb+96];
    const float co = c_st[b2*512 + k2];
    const float cn = sigmf(zf)*co + sigmf(zi)*tanhf(zg);
    const float hn = sigmf(zo)*tanhf(cn);
    c_st[b2*512 + k2] = cn;
    h_f32[b2*512 + k2] = hn;
    if (h_seq)  h_seq[b2*512 + k2] = hn;
    if (h_bf16) h_bf16[b2*1024 + k2] = f2bf(hn);
  }
}

// encoder step: both directions in one launch (blockIdx.y = dir)
__global__ __launch_bounds__(256) void k_enc_step(
    const float* __restrict__ pre_f, const float* __restrict__ pre_b,
    const float* __restrict__ Whh_f, const float* __restrict__ Whh_b,
    const float* __restrict__ hr_f, float* __restrict__ hw_f, float* __restrict__ c_f, float* __restrict__ outs_f,
    const float* __restrict__ hr_b, float* __restrict__ hw_b, float* __restrict__ c_b, float* __restrict__ outs_b)
{
  __shared__ __align__(16) float x_lds[32*260];
  __shared__ float zbuf[256];
  if (blockIdx.y == 0)
    step_core(pre_f, nullptr, nullptr, hr_f, Whh_f, 512, nullptr, nullptr, 0,
              c_f, hw_f, outs_f, nullptr, x_lds, zbuf, blockIdx.x);
  else
    step_core(pre_b, nullptr, nullptr, hr_b, Whh_b, 512, nullptr, nullptr, 0,
              c_b, hw_b, outs_b, nullptr, x_lds, zbuf, blockIdx.x);
}

// decoder cell
__global__ __launch_bounds__(256) void k_dec_cell(
    const float* __restrict__ pre, const float* __restrict__ bias0, const float* __restrict__ bias1,
    const float* __restrict__ xa, const float* __restrict__ Wa, int ldwa,
    const float* __restrict__ xb, const float* __restrict__ Wb, int ldwb,
    float* __restrict__ c_st, float* __restrict__ h_f32, short* __restrict__ h_bf16)
{
  __shared__ __align__(16) float x_lds[32*260];
  __shared__ float zbuf[256];
  step_core(pre, bias0, bias1, xa, Wa, ldwa, xb, Wb, ldwb,
            c_st, h_f32, nullptr, h_bf16, x_lds, zbuf, blockIdx.x);
}

// ---------------------------------------------------------------------------
// enc_sum = f_outs[s] + b_outs[127-s]; also emit bf16 copy. grid 8192x256.
__global__ __launch_bounds__(256) void k_sum_enc(
    const float* __restrict__ f_outs, const float* __restrict__ b_outs,
    float* __restrict__ enc_sum, short* __restrict__ enc_sum_bf)
{
  const int i = blockIdx.x*256 + threadIdx.x;     // < 2,097,152
  const int s = i >> 14, rem = i & 16383;
  const float v = f_outs[i] + b_outs[(size_t)(127 - s)*16384 + rem];
  enc_sum[i] = v;
  enc_sum_bf[i] = f2bf(v);
}

// ---------------------------------------------------------------------------
// qproj[b][col] = sum_k h1[b][k] * attnW[col][k]   (Wq = attn_W[:, :512])
// grid 64 blocks: block covers 8 cols x 32 b.
__global__ __launch_bounds__(256) void k_qproj(
    const float* __restrict__ h1, const float* __restrict__ attnW, float* __restrict__ qproj)
{
  __shared__ __align__(16) float h_lds[32*260];
  for (int i = threadIdx.x; i < 4096; i += 256){
    const int bb = i >> 7, kk = (i & 127) << 2;
    *(float4*)&h_lds[bb*260 + kk] = *(const float4*)&h1[bb*512 + kk];
  }
  __syncthreads();
  const int b = threadIdx.x & 31, ci = threadIdx.x >> 5;
  const int col = blockIdx.x * 8 + ci;
  const float* wrow = attnW + (size_t)col * 1024;
  const float* hx = &h_lds[b*260];
  float4 s4 = {0.f,0.f,0.f,0.f};
  #pragma unroll 4
  for (int kk = 0; kk < 512; kk += 4){
    const float4 wv = *(const float4*)&wrow[kk];
    const float4 hv = *(const float4*)&hx[kk];
    s4.x = fmaf(wv.x, hv.x, s4.x);
    s4.y = fmaf(wv.y, hv.y, s4.y);
    s4.z = fmaf(wv.z, hv.z, s4.z);
    s4.w = fmaf(wv.w, hv.w, s4.w);
  }
  qproj[b*512 + col] = (s4.x + s4.y) + (s4.z + s4.w);
}

// ---------------------------------------------------------------------------
// attention scores+softmax+ctx for one decoder step. grid 32 blocks (b).
__global__ __launch_bounds__(256) void k_attn(
    const float* __restrict__ qproj, const float* __restrict__ enc_proj,
    const float* __restrict__ attnV, const float* __restrict__ enc_sum,
    float* __restrict__ ctx, short* __restrict__ h1ctx_t)
{
  const int b = blockIdx.x, tid = threadIdx.x;
  __shared__ float q_s[512], v_s[512];
  __shared__ float part[256];
  __shared__ float aw[128];
  __shared__ float red[128];
  for (int i = tid; i < 512; i += 256){ q_s[i] = qproj[b*512 + i]; v_s[i] = attnV[i]; }
  __syncthreads();
  {
    const int s = tid >> 1, half = tid & 1;
    const float* ep = enc_proj + ((size_t)(s*32 + b))*512 + (half << 8);
    const float* qh = q_s + (half << 8);
    const float* vh = v_s + (half << 8);
    float p = 0.f;
    for (int kk = 0; kk < 256; kk += 4){
      const float4 e = *(const float4*)&ep[kk];
      p += tanhf(qh[kk+0] + e.x) * vh[kk+0];
      p += tanhf(qh[kk+1] + e.y) * vh[kk+1];
      p += tanhf(qh[kk+2] + e.z) * vh[kk+2];
      p += tanhf(qh[kk+3] + e.w) * vh[kk+3];
    }
    part[tid] = p;
  }
  __syncthreads();
  if (tid < 128){ const float sc = part[2*tid] + part[2*tid+1]; aw[tid] = sc; red[tid] = sc; }
  __syncthreads();
  for (int off = 64; off > 0; off >>= 1){
    if (tid < off) red[tid] = fmaxf(red[tid], red[tid+off]);
    __syncthreads();
  }
  const float m = red[0];
  __syncthreads();
  if (tid < 128){ const float e = __expf(aw[tid] - m); aw[tid] = e; red[tid] = e; }
  __syncthreads();
  for (int off = 64; off > 0; off >>= 1){
    if (tid < off) red[tid] += red[tid+off];
    __syncthreads();
  }
  const float inv = 1.0f / red[0];
  if (tid < 128) aw[tid] *= inv;
  __syncthreads();
  {
    const int c0 = tid << 1;
    float x0 = 0.f, x1 = 0.f;
    for (int s = 0; s < 128; ++s){
      const float a = aw[s];
      const float* er = enc_sum + ((size_t)(s*32 + b))*512 + c0;
      x0 = fmaf(a, er[0], x0);
      x1 = fmaf(a, er[1], x1);
    }
    ctx[b*512 + c0]     = x0;
    ctx[b*512 + c0 + 1] = x1;
    h1ctx_t[b*1024 + 512 + c0]     = f2bf(x0);
    h1ctx_t[b*1024 + 512 + c0 + 1] = f2bf(x1);
  }
}

// ---------------------------------------------------------------------------
// in-place log_softmax over rows of 32000. grid 992 blocks.
__global__ __launch_bounds__(256) void k_logsm(float* __restrict__ out){
  float* row = out + (size_t)blockIdx.x * 32000;
  const int tid = threadIdx.x;
  __shared__ float red[256];
  float m = -3.4e38f;
  for (int i = tid; i < 32000; i += 256) m = fmaxf(m, row[i]);
  red[tid] = m; __syncthreads();
  for (int off = 128; off > 0; off >>= 1){
    if (tid < off) red[tid] = fmaxf(red[tid], red[tid+off]);
    __syncthreads();
  }
  m = red[0]; __syncthreads();
  float s = 0.f;
  for (int i = tid; i < 32000; i += 256) s += __expf(row[i] - m);
  red[tid] = s; __syncthreads();
  for (int off = 128; off > 0; off >>= 1){
    if (tid < off) red[tid] += red[tid+off];
    __syncthreads();
  }
  const float lse = m + __logf(red[0]);
  for (int i = tid; i < 32000; i += 256) row[i] -= lse;
}

// ---------------------------------------------------------------------------
extern "C" void kernel_launch(void* const* d_in, const int* in_sizes, int n_in,
                              void* d_out, int out_size, void* d_ws, size_t ws_size,
                              hipStream_t stream)
{
  (void)in_sizes; (void)n_in; (void)out_size; (void)ws_size;
  const int*   src   = (const int*)d_in[0];
  const int*   trg   = (const int*)d_in[1];
  const float* embed = (const float*)d_in[2];
  const float* eWihF = (const float*)d_in[3];
  const float* eWhhF = (const float*)d_in[4];
  const float* ebihF = (const float*)d_in[5];
  const float* ebhhF = (const float*)d_in[6];
  const float* eWihB = (const float*)d_in[7];
  const float* eWhhB = (const float*)d_in[8];
  const float* ebihB = (const float*)d_in[9];
  const float* ebhhB = (const float*)d_in[10];
  const float* attnW = (const float*)d_in[11];
  const float* attnB = (const float*)d_in[12];
  const float* attnV = (const float*)d_in[13];
  const float* dWih0 = (const float*)d_in[14];
  const float* dWhh0 = (const float*)d_in[15];
  const float* dbih0 = (const float*)d_in[16];
  const float* dbhh0 = (const float*)d_in[17];
  const float* dWih1 = (const float*)d_in[18];
  const float* dWhh1 = (const float*)d_in[19];
  const float* dbih1 = (const float*)d_in[20];
  const float* dbhh1 = (const float*)d_in[21];
  const float* outW  = (const float*)d_in[22];
  const float* outB  = (const float*)d_in[23];

  float* out = (float*)d_out;
  // ---- d_out used as scratch; every region dies before the final GEMM+logsm
  float* enc_in_f = out;               // [128][32][2048]
  float* enc_in_b = out + 8388608;     // [128][32][2048]
  float* enc_sum  = out + 16777216;    // [128][32][512]
  float* enc_proj = out + 18874368;    // [128*32][512]
  float* f_outs   = out + 20971520;    // [128][32][512]
  float* b_outs   = out + 23068672;    // [128][32][512]
  float* demb     = out + 25165824;    // [1024][2048]
  short* emb_src_bf = (short*)(out + 27262976);  // [4096][256] bf16
  short* emb_trg_bf = (short*)(out + 27787264);  // [1024][256] bf16
  short* enc_sum_bf = (short*)(out + 27918336);  // [4096][512] bf16

  char* ws = (char*)d_ws;
  short* h1ctx = (short*)ws;                  // [1024][1024] bf16 (rows 992.. unused)
  float* st    = (float*)(ws + 2097152);
  float* h_f0 = st;           float* h_f1 = st + 16384;
  float* h_b0 = st + 32768;   float* h_b1 = st + 49152;
  float* c_f  = st + 65536;   float* c_b  = st + 81920;
  float* qproj= st + 98304;   float* ctx  = st + 114688;
  float* hf[2] = {h_f0, h_f1};
  float* hb[2] = {h_b0, h_b1};

  // 1. zero LSTM states (+qproj/ctx)
  k_zero<<<64, 256, 0, stream>>>(st, 131072);
  // 2. embedding gathers
  k_gather<<<5120, 256, 0, stream>>>(src, trg, embed, emb_src_bf, emb_trg_bf);
  // 3. batched input projections
  {
    dim3 g1(32,16);
    k_gemm_aw<<<g1,256,0,stream>>>(emb_src_bf,256, eWihF,256, enc_in_f,2048, ebihF,ebhhF, 4096,256);
    k_gemm_aw<<<g1,256,0,stream>>>(emb_src_bf,256, eWihB,256, enc_in_b,2048, ebihB,ebhhB, 4096,256);
    dim3 g2(8,16);
    k_gemm_aw<<<g2,256,0,stream>>>(emb_trg_bf,256, dWih0,768, demb,2048, dbih0,dbhh0, 1024,256);
  }
  // 4. encoder (fwd+bwd fused per step)
  for (int t = 0; t < 128; ++t){
    const int pr = t & 1;
    k_enc_step<<<dim3(256,2),256,0,stream>>>(
      enc_in_f + (size_t)t*65536, enc_in_b + (size_t)(127-t)*65536,
      eWhhF, eWhhB,
      hf[pr], hf[pr^1], c_f, f_outs + (size_t)t*16384,
      hb[pr], hb[pr^1], c_b, b_outs + (size_t)t*16384);
  }
  // 5. sum directions (+bf16 copy).  hf[0]=final fwd h, hb[0]=final bwd h, c_f/c_b carry.
  k_sum_enc<<<8192,256,0,stream>>>(f_outs, b_outs, enc_sum, enc_sum_bf);
  // 6. attention enc projection (+attn_b folded in)
  {
    dim3 g3(32,4);
    k_gemm_aw<<<g3,256,0,stream>>>(enc_sum_bf,512, attnW+512,1024, enc_proj,512, attnB,nullptr, 4096,512);
  }
  // 7. decoder: 31 steps
  for (int t = 0; t < 31; ++t){
    const int pr = t & 1;
    k_qproj<<<64,256,0,stream>>>(hb[pr], attnW, qproj);
    k_attn <<<32,256,0,stream>>>(qproj, enc_proj, attnV, enc_sum, ctx, h1ctx + (size_t)t*32768);
    k_dec_cell<<<256,256,0,stream>>>(demb + (size_t)t*65536, nullptr, nullptr,
      ctx, dWih0+256, 768, hf[pr], dWhh0, 512, c_f, hf[pr^1], nullptr);
    k_dec_cell<<<256,256,0,stream>>>(nullptr, dbih1, dbhh1,
      hf[pr^1], dWih1, 512, hb[pr], dWhh1, 512, c_b, hb[pr^1], h1ctx + (size_t)t*32768);
  }
  // 8. outputs[0] = 0
  k_zero<<<512,256,0,stream>>>(out, 1024000);
  // 9. batched output projection: [992,1024] @ [1024,32000]^T + out_b
  {
    dim3 g4(8,250);
    k_gemm_aw<<<g4,256,0,stream>>>(h1ctx,1024, outW,1024, out + 1024000, 32000, outB,nullptr, 992,1024);
  }
  // 10. in-place log_softmax on rows 32..1023
  k_logsm<<<992,256,0,stream>>>(out + 1024000);
}